// Round 7
// baseline (257.508 us; speedup 1.0000x reference)
//
#include <hip/hip_runtime.h>

#define NSTEPS 10
#define D_IN   14400
#define KNN_K  25

// layer dims
#define L0D 7200
#define L1D 3600
#define L2D 1800
#define L3D 900
#define L4D 450

// 64-row groups per layer; 13 uint2 slots x 64 lanes per group
#define G0 113
#define G1 57
#define G2 29
#define G3 15
#define G4 8
#define SPG 832
#define O1 (G0*SPG)
#define O2 (O1 + G1*SPG)
#define O3 (O2 + G2*SPG)
#define O4 (O3 + G3*SPG)
#define OTOT (O4 + G4*SPG)     // 184704 uint2

// 64-aligned half-splits
#define SPLIT0 3584
#define SPLIT1 1792
#define SPLIT2 896

// round-to-nearest-even f32 -> bf16 bits
__device__ __forceinline__ unsigned bf16b(float x) {
    unsigned u = __float_as_uint(x);
    return (u + 0x7fffu + ((u >> 16) & 1u)) >> 16;
}

// one (idx,w): u = (bf16_w << 16) | idx ; act word = bf16 b0 | bf16 b1 << 16
__device__ __forceinline__ void gpair(unsigned u, const unsigned* __restrict__ Xin,
                                      float& s0, float& s1) {
    unsigned av = Xin[u & 0xffffu];                   // ds_read_b32 random
    float wf = __uint_as_float(u & 0xffff0000u);
    s0 = fmaf(__uint_as_float(av << 16),          wf, s0);
    s1 = fmaf(__uint_as_float(av & 0xffff0000u),  wf, s1);
}

// ---- prep: lane-major SoA weight tiles + zero the sync flags ----
__global__ void prep_kernel(const int* __restrict__ k0, const float* __restrict__ w0,
                            const int* __restrict__ k1, const float* __restrict__ w1,
                            const int* __restrict__ k2, const float* __restrict__ w2,
                            const int* __restrict__ k3, const float* __restrict__ w3,
                            const int* __restrict__ k4, const float* __restrict__ w4,
                            uint2* __restrict__ tile, unsigned* __restrict__ flags)
{
    // FIX (r6 bug): block is 256 threads, so use 3 blocks to zero all 768 flags
    if (blockIdx.x < 3) flags[blockIdx.x * 256 + threadIdx.x] = 0;
    int s = blockIdx.x * 256 + threadIdx.x;
    if (s >= OTOT) return;
    const int* kp; const float* wp; int dim, t;
    if      (s < O1) { kp = k0; wp = w0; dim = L0D; t = s;      }
    else if (s < O2) { kp = k1; wp = w1; dim = L1D; t = s - O1; }
    else if (s < O3) { kp = k2; wp = w2; dim = L2D; t = s - O2; }
    else if (s < O4) { kp = k3; wp = w3; dim = L3D; t = s - O3; }
    else             { kp = k4; wp = w4; dim = L4D; t = s - O4; }
    int g    = t / SPG;
    int rem  = t - g * SPG;
    int j    = rem >> 6;
    int lane = rem & 63;
    int r    = g * 64 + lane;
    unsigned vx = 0, vy = 0;
    if (r < dim) {
        int e0 = 2 * j, e1 = 2 * j + 1;
        if (e0 < KNN_K) vx = (bf16b(wp[r * KNN_K + e0]) << 16) | (unsigned)kp[r * KNN_K + e0];
        if (e1 < KNN_K) vy = (bf16b(wp[r * KNN_K + e1]) << 16) | (unsigned)kp[r * KNN_K + e1];
    }
    tile[s] = make_uint2(vx, vy);
}

// ---- one gather layer over row range [lo,hi), write LDS (+optional global) ----
template<int MAXI>
__device__ __forceinline__ void glayer(const unsigned* __restrict__ Xin,
                                       unsigned* __restrict__ Yl,
                                       unsigned* __restrict__ Yg,
                                       const uint2* __restrict__ tbase,
                                       const float* __restrict__ bias,
                                       int lo, int hi, int tid)
{
#pragma unroll
    for (int i = 0; i < MAXI; ++i) {
        int r = lo + tid + i * 1024;
        if (r < hi) {
            const uint2* tp = tbase + (size_t)(r >> 6) * SPG + (r & 63);
            float a = bias[r], b = a, c = 0.f, d = 0.f;
#pragma unroll
            for (int j = 0; j < 13; ++j) {
                uint2 u = tp[j * 64];              // coalesced 512B/wave, L2-resident
                gpair(u.x, Xin, a, b);
                gpair(u.y, Xin, c, d);
            }
            a += c; b += d;
            unsigned wv = bf16b(a) | (bf16b(b) << 16);
            Yl[r] = wv;
            if (Yg) Yg[r] = wv;
        }
    }
}

// ---- pair half-exchange: release own half, acquire peer half, stage to LDS ----
__device__ __forceinline__ void xchg(unsigned* __restrict__ flags, int round,
                                     int bid, int tid,
                                     const unsigned* __restrict__ Yg_pair,
                                     unsigned* __restrict__ Yl,
                                     int lo_peer, int hi_peer)
{
    __threadfence();                               // each thread's global writes -> agent
    __syncthreads();
    if (tid == 0) {
        __hip_atomic_store(flags + round * 256 + bid, 1u,
                           __ATOMIC_RELEASE, __HIP_MEMORY_SCOPE_AGENT);
        while (__hip_atomic_load(flags + round * 256 + (bid ^ 128),
                                 __ATOMIC_ACQUIRE, __HIP_MEMORY_SCOPE_AGENT) == 0u)
            __builtin_amdgcn_s_sleep(2);
    }
    __syncthreads();
    for (int r = lo_peer + tid; r < hi_peer; r += 1024)
        Yl[r] = Yg_pair[r];
    __syncthreads();
}

// ---- persistent fused network: 256 blocks = 128 pairs x 2 halves ----
__global__ __launch_bounds__(1024)
void lcn_mega(const float* __restrict__ input, const uint2* __restrict__ tile,
              const float* __restrict__ b0, const float* __restrict__ b1,
              const float* __restrict__ b2, const float* __restrict__ b3,
              const float* __restrict__ b4,
              const float* __restrict__ fc_w, const float* __restrict__ fc_b,
              unsigned* __restrict__ y0g, unsigned* __restrict__ y1g,
              unsigned* __restrict__ y2g, unsigned* __restrict__ flags,
              float* __restrict__ out)
{
    __shared__ unsigned sm[D_IN + L0D];            // 86.4 KB -> exactly 1 block/CU
    unsigned* X  = sm;                             // [0, 14400)
    unsigned* Y0 = sm + D_IN;                      // [14400, 21600)
    unsigned* Y1 = sm;                             // reuse X space: [0, 3600)
    unsigned* Y2 = sm + 3600;                      // [3600, 5400)
    unsigned* Y3 = sm + 5400;                      // [5400, 6300)
    float*    Y4 = (float*)(sm + 6300);            // [6300, 6750) f32, own batch

    const int tid = threadIdx.x;
    const int bid = blockIdx.x;
    const int p   = bid & 127;                     // pair id; peer = bid ^ 128 (same XCD)
    const int h   = bid >> 7;                      // neuron-half

    // ---- pack input pair (rows 2p, 2p+1 last step) into X as 2-batch bf16 words ----
    {
        const float4* r0 = (const float4*)(input + ((size_t)(2 * p)     * NSTEPS + NSTEPS - 1) * D_IN);
        const float4* r1 = (const float4*)(input + ((size_t)(2 * p + 1) * NSTEPS + NSTEPS - 1) * D_IN);
        for (int i = tid; i < D_IN / 4; i += 1024) {
            float4 a = r0[i], c = r1[i];
            uint4 wd;
            wd.x = bf16b(a.x) | (bf16b(c.x) << 16);
            wd.y = bf16b(a.y) | (bf16b(c.y) << 16);
            wd.z = bf16b(a.z) | (bf16b(c.z) << 16);
            wd.w = bf16b(a.w) | (bf16b(c.w) << 16);
            *(uint4*)(X + 4 * i) = wd;
        }
    }
    __syncthreads();

    // ---- L0 (split) + exchange ----
    unsigned* myY0g = y0g + (size_t)p * L0D;
    glayer<4>(X, Y0, myY0g, tile, b0, h ? SPLIT0 : 0, h ? L0D : SPLIT0, tid);
    xchg(flags, 0, bid, tid, myY0g, Y0, h ? 0 : SPLIT0, h ? SPLIT0 : L0D);

    // ---- L1 (split) + exchange ----
    unsigned* myY1g = y1g + (size_t)p * L1D;
    glayer<2>(Y0, Y1, myY1g, tile + O1, b1, h ? SPLIT1 : 0, h ? L1D : SPLIT1, tid);
    xchg(flags, 1, bid, tid, myY1g, Y1, h ? 0 : SPLIT1, h ? SPLIT1 : L1D);

    // ---- L2 (split) + exchange ----
    unsigned* myY2g = y2g + (size_t)p * L2D;
    glayer<1>(Y1, Y2, myY2g, tile + O2, b2, h ? SPLIT2 : 0, h ? L2D : SPLIT2, tid);
    xchg(flags, 2, bid, tid, myY2g, Y2, h ? 0 : SPLIT2, h ? SPLIT2 : L2D);

    // ---- L3 full (redundant on both halves, LDS-only) ----
    glayer<1>(Y2, Y3, nullptr, tile + O3, b3, 0, L3D, tid);
    __syncthreads();

    // ---- L4 full, keep own batch in f32 ----
    if (tid < L4D) {
        const uint2* tp = tile + O4 + (size_t)(tid >> 6) * SPG + (tid & 63);
        float a = b4[tid], b = a, c = 0.f, d = 0.f;
#pragma unroll
        for (int j = 0; j < 13; ++j) {
            uint2 u = tp[j * 64];
            gpair(u.x, Y3, a, b);
            gpair(u.y, Y3, c, d);
        }
        a += c; b += d;
        Y4[tid] = h ? b : a;
    }
    __syncthreads();

    // ---- FC head: 2 waves, one per output channel, batch = 2p+h ----
    if (tid < 128) {
        const int o = tid >> 6, lane = tid & 63;
        float s = 0.f;
#pragma unroll
        for (int it = 0; it < 8; ++it) {
            int r = lane + it * 64;
            if (r < L4D) s += Y4[r] * fc_w[o * L4D + r];
        }
#pragma unroll
        for (int off = 32; off > 0; off >>= 1) s += __shfl_xor(s, off);
        if (lane == 0) out[(2 * p + h) * 2 + o] = s + fc_b[o];
    }
}

extern "C" void kernel_launch(void* const* d_in, const int* in_sizes, int n_in,
                              void* d_out, int out_size, void* d_ws, size_t ws_size,
                              hipStream_t stream) {
    const float* input = (const float*)d_in[0];
    const int*   knn[5];
    const float* w[5];
    const float* bias[5];
    for (int i = 0; i < 5; ++i) {
        knn[i]  = (const int*)  d_in[1 + 3 * i];
        w[i]    = (const float*)d_in[2 + 3 * i];
        bias[i] = (const float*)d_in[3 + 3 * i];
    }
    const float* fc_w = (const float*)d_in[16];
    const float* fc_b = (const float*)d_in[17];
    float* out = (float*)d_out;

    // ws layout (16B-aligned): tile | flags(4KB) | y0 | y1 | y2
    char* base = (char*)d_ws;
    uint2*    tile  = (uint2*)base;                                    // 1.478 MB
    unsigned* flags = (unsigned*)(base + (size_t)OTOT * 8);            // 3 KB (pad 4KB)
    unsigned* y0g   = (unsigned*)(base + (size_t)OTOT * 8 + 4096);     // 3.686 MB
    unsigned* y1g   = y0g + (size_t)128 * L0D;                         // 1.843 MB
    unsigned* y2g   = y1g + (size_t)128 * L1D;                         // 0.922 MB

    prep_kernel<<<(OTOT + 255) / 256, 256, 0, stream>>>(
        knn[0], w[0], knn[1], w[1], knn[2], w[2], knn[3], w[3], knn[4], w[4],
        tile, flags);

    lcn_mega<<<256, 1024, 0, stream>>>(
        input, tile, bias[0], bias[1], bias[2], bias[3], bias[4],
        fc_w, fc_b, y0g, y1g, y2g, flags, out);
}

// Round 8
// 40.770 us; speedup vs baseline: 6.3162x; 6.3162x over previous
//
#include <hip/hip_runtime.h>

#define NSTEPS 10
#define D_IN   14400
#define KNN_K  25

// layer dims
#define L0D 7200
#define L1D 3600
#define L2D 1800
#define L3D 900
#define L4D 450
#define NROWS 13950   // total neurons across all 5 layers

// 64-row groups per layer; 13 uint2 slots x 64 lanes per group
#define G0 113
#define G1 57
#define G2 29
#define G3 15
#define G4 8
#define SPG 832
#define O1 (G0*SPG)
#define O2 (O1 + G1*SPG)
#define O3 (O2 + G2*SPG)
#define O4 (O3 + G3*SPG)
#define OTOT (O4 + G4*SPG)      // 184704 uint2

#define NPAIR 128
#define NPACK (NPAIR * (D_IN/4))  // 460800 pack items (uint4-pair each)

// 64-aligned l0 half-split
#define SPLIT0 3584

// round-to-nearest-even f32 -> bf16 bits
__device__ __forceinline__ unsigned bf16b(float x) {
    unsigned u = __float_as_uint(x);
    return (u + 0x7fffu + ((u >> 16) & 1u)) >> 16;
}

// one (idx,w): u = (bf16_w << 16) | (idx << 2)  [byte offset, max 57596 fits 16b]
// act word = bf16 b0 | bf16 b1 << 16
__device__ __forceinline__ void gpairB(unsigned u, const char* __restrict__ actb,
                                       float& s0, float& s1) {
    unsigned av = *(const unsigned*)(actb + (u & 0xffffu));   // random ds_read_b32
    float wf = __uint_as_float(u & 0xffff0000u);
    s0 = fmaf(__uint_as_float(av << 16),          wf, s0);
    s1 = fmaf(__uint_as_float(av & 0xffff0000u),  wf, s1);
}

// ---- prep: (A) per-row BANK-BALANCED permuted weight tiles, (B) pack input 2-batch bf16 ----
// Permutation theory: slot(k) = (bankrank(k) + lane%25) % 25 makes slot j across the
// 64 lanes of a gather wave sample bank-ranks 0..24 cyclically -> banks spread over
// the full 0..31 range -> expected max bank load ~3 instead of ~4.3 for random.
// Dot product is order-invariant, so any per-row permutation is correct by construction.
__global__ void prep_kernel(const int* __restrict__ k0, const float* __restrict__ w0,
                            const int* __restrict__ k1, const float* __restrict__ w1,
                            const int* __restrict__ k2, const float* __restrict__ w2,
                            const int* __restrict__ k3, const float* __restrict__ w3,
                            const int* __restrict__ k4, const float* __restrict__ w4,
                            const float* __restrict__ input,
                            uint2* __restrict__ tile, uint4* __restrict__ xpk)
{
    const int s = blockIdx.x * 256 + threadIdx.x;
    if (s < NROWS) {
        // ---- tile build with bank-balancing permutation ----
        const int* kp; const float* wp; int dl, obase;
        if      (s < L0D)             { kp = k0; wp = w0; dl = s;         obase = 0;  }
        else if (s < L0D+L1D)         { kp = k1; wp = w1; dl = s - L0D;   obase = O1; }
        else if (s < L0D+L1D+L2D)     { kp = k2; wp = w2; dl = s-L0D-L1D; obase = O2; }
        else if (s < L0D+L1D+L2D+L3D) { kp = k3; wp = w3; dl = s-L0D-L1D-L2D; obase = O3; }
        else                          { kp = k4; wp = w4; dl = s-L0D-L1D-L2D-L3D; obase = O4; }
        const int g = dl >> 6, l = dl & 63;

        int   idx[KNN_K]; float wv[KNN_K]; int bk[KNN_K];
#pragma unroll
        for (int k = 0; k < KNN_K; ++k) {
            idx[k] = kp[dl * KNN_K + k];
            wv[k]  = wp[dl * KNN_K + k];
            bk[k]  = idx[k] & 31;
        }
        const int lm = l - (l >= 50 ? 50 : (l >= 25 ? 25 : 0));   // l % 25
        unsigned* tw = (unsigned*)tile + 2u * (unsigned)(obase + g * SPG);
#pragma unroll
        for (int k = 0; k < KNN_K; ++k) {
            int rank = 0;
#pragma unroll
            for (int j = 0; j < KNN_K; ++j)
                rank += (bk[j] < bk[k]) || (bk[j] == bk[k] && j < k);
            int slot = rank + lm; if (slot >= KNN_K) slot -= KNN_K;
            unsigned u = (bf16b(wv[k]) << 16) | ((unsigned)idx[k] << 2);
            tw[((slot >> 1) * 64 + l) * 2 + (slot & 1)] = u;
        }
        tw[(12 * 64 + l) * 2 + 1] = 0;   // pad slot 25 = zero weight
        return;
    }
    // ---- input pack: 2-batch bf16 words, pair-major ----
    const int t = s - NROWS;
    if (t < NPACK) {
        const int p = t / (D_IN / 4);
        const int c = t - p * (D_IN / 4);
        const float4 a = *(const float4*)(input + ((size_t)(2*p)   * NSTEPS + NSTEPS-1) * D_IN + 4*c);
        const float4 b = *(const float4*)(input + ((size_t)(2*p+1) * NSTEPS + NSTEPS-1) * D_IN + 4*c);
        uint4 wd;
        wd.x = bf16b(a.x) | (bf16b(b.x) << 16);
        wd.y = bf16b(a.y) | (bf16b(b.y) << 16);
        wd.z = bf16b(a.z) | (bf16b(b.z) << 16);
        wd.w = bf16b(a.w) | (bf16b(b.w) << 16);
        xpk[(size_t)p * (D_IN / 4) + c] = wd;
    }
}

// ---- layer 0: 256 blocks = 128 pairs x 2 neuron-halves; packed input staged to LDS ----
__global__ __launch_bounds__(512, 2)
void lcn_l0(const uint4* __restrict__ xpk, const uint2* __restrict__ tile,
            const float* __restrict__ bias0, unsigned* __restrict__ y0)
{
    __shared__ unsigned act[D_IN];          // 57.6 KB -> 2 blocks/CU
    const int tid = threadIdx.x;
    const int p   = blockIdx.x & 127;
    const int h   = blockIdx.x >> 7;

    const uint4* src = xpk + (size_t)p * (D_IN / 4);
    for (int i = tid; i < D_IN / 4; i += 512)
        *(uint4*)(act + i * 4) = src[i];
    __syncthreads();
    const char* actb = (const char*)act;

    const int rbase = h ? SPLIT0 : 0;
    const int rend  = h ? L0D    : SPLIT0;
#pragma unroll
    for (int i = 0; i < 8; ++i) {
        int r = rbase + tid + i * 512;
        if (r < rend) {
            const uint2* tp = tile + (size_t)(r >> 6) * SPG + (r & 63);
            float a = bias0[r], b = a, c = 0.f, d = 0.f;
#pragma unroll
            for (int j = 0; j < 13; ++j) {
                uint2 u = tp[j * 64];       // coalesced 512B/wave, L2-resident
                gpairB(u.x, actb, a, b);
                gpairB(u.y, actb, c, d);
            }
            a += c; b += d;
            y0[(size_t)p * L0D + r] = bf16b(a) | (bf16b(b) << 16);
        }
    }
}

// ---- one gather layer inside the tail kernel ----
template<int DIM>
__device__ __forceinline__ void glayerT(const char* __restrict__ actb,
                                        unsigned* __restrict__ yout,
                                        const uint2* __restrict__ tb,
                                        const float* __restrict__ bias, int tid)
{
#pragma unroll
    for (int i = 0; i < (DIM + 1023) / 1024; ++i) {
        int r = tid + i * 1024;
        if (r < DIM) {
            const uint2* tp = tb + (size_t)(r >> 6) * SPG + (r & 63);
            float a = bias[r], b = a, c = 0.f, d = 0.f;
#pragma unroll
            for (int j = 0; j < 13; ++j) {
                uint2 u = tp[j * 64];
                gpairB(u.x, actb, a, b);
                gpairB(u.y, actb, c, d);
            }
            a += c; b += d;
            yout[r] = bf16b(a) | (bf16b(b) << 16);
        }
    }
}

// ---- tail: L1..L4 + FC, one block per pair, everything in LDS (disjoint regions) ----
__global__ __launch_bounds__(1024)
void lcn_tail(const unsigned* __restrict__ y0, const uint2* __restrict__ tile,
              const float* __restrict__ b1, const float* __restrict__ b2,
              const float* __restrict__ b3, const float* __restrict__ b4,
              const float* __restrict__ fc_w, const float* __restrict__ fc_b,
              float* __restrict__ out)
{
    __shared__ unsigned sm[L0D + L1D];      // 43.2 KB
    const int tid = threadIdx.x;
    const int p   = blockIdx.x;

    // stage y0 -> sm[0:7200)
    const uint4* src = (const uint4*)(y0 + (size_t)p * L0D);
    for (int i = tid; i < L0D / 4; i += 1024)
        *(uint4*)(sm + 4 * i) = src[i];
    __syncthreads();

    // L1: read [0:7200) -> write [7200:10800)
    glayerT<L1D>((const char*)sm,         sm + L0D,        tile + O1, b1, tid);
    __syncthreads();
    // L2: read [7200:10800) -> write [0:1800)
    glayerT<L2D>((const char*)(sm + L0D), sm,              tile + O2, b2, tid);
    __syncthreads();
    // L3: read [0:1800) -> write [1800:2700)
    glayerT<L3D>((const char*)sm,         sm + L2D,        tile + O3, b3, tid);
    __syncthreads();
    // L4: read [1800:2700) -> write [2700:3150)
    glayerT<L4D>((const char*)(sm + L2D), sm + L2D + L3D,  tile + O4, b4, tid);
    __syncthreads();

    // FC: 4 waves -> (out o, batch-in-pair j)
    const unsigned* C = sm + L2D + L3D;
    if (tid < 256) {
        const int wv = tid >> 6, lane = tid & 63;
        const int o = wv >> 1, j = wv & 1;
        float s = 0.f;
#pragma unroll
        for (int it = 0; it < 8; ++it) {
            int r = lane + it * 64;
            if (r < L4D) {
                unsigned av = C[r];
                unsigned hbits = j ? (av & 0xffff0000u) : (av << 16);
                s += __uint_as_float(hbits) * fc_w[o * L4D + r];
            }
        }
#pragma unroll
        for (int off = 32; off > 0; off >>= 1) s += __shfl_xor(s, off);
        if (lane == 0) out[(2 * p + j) * 2 + o] = s + fc_b[o];
    }
}

extern "C" void kernel_launch(void* const* d_in, const int* in_sizes, int n_in,
                              void* d_out, int out_size, void* d_ws, size_t ws_size,
                              hipStream_t stream) {
    const float* input = (const float*)d_in[0];
    const int*   knn[5];
    const float* w[5];
    const float* bias[5];
    for (int i = 0; i < 5; ++i) {
        knn[i]  = (const int*)  d_in[1 + 3 * i];
        w[i]    = (const float*)d_in[2 + 3 * i];
        bias[i] = (const float*)d_in[3 + 3 * i];
    }
    const float* fc_w = (const float*)d_in[16];
    const float* fc_b = (const float*)d_in[17];
    float* out = (float*)d_out;

    // ws layout (16B-aligned): tile | xpk | y0
    char* base = (char*)d_ws;
    uint2*    tile = (uint2*)base;                                   // 1.478 MB
    uint4*    xpk  = (uint4*)(base + (size_t)OTOT * 8);              // 7.373 MB
    unsigned* y0   = (unsigned*)((char*)xpk + (size_t)NPAIR * D_IN * 4); // 3.686 MB

    const int nprep = NROWS + NPACK;
    prep_kernel<<<(nprep + 255) / 256, 256, 0, stream>>>(
        knn[0], w[0], knn[1], w[1], knn[2], w[2], knn[3], w[3], knn[4], w[4],
        input, tile, xpk);

    lcn_l0<<<256, 512, 0, stream>>>(xpk, tile, bias[0], y0);

    lcn_tail<<<NPAIR, 1024, 0, stream>>>(y0, tile, bias[1], bias[2], bias[3], bias[4],
                                         fc_w, fc_b, out);
}